// Round 2
// baseline (268.699 us; speedup 1.0000x reference)
//
#include <hip/hip_runtime.h>

#define NIMG   48
#define H      512
#define W      512
#define CH     34
#define CHUNKS 16
#define NTHR   256
#define LDSW   268          // 266 needed (256 cols + 2*5 halo), pad to 268
#define NBLOCK (NIMG * CHUNKS * 2)   // 1536 = 6 blocks/CU exactly
#define NPIX   12582912.0f

__device__ __forceinline__ int refl(int x) {
    x = (x < 0) ? -x : x;
    return (x >= 512) ? (1022 - x) : x;
}

// Gaussian weights for sigma=1.5, window 11 (precomputed, matches fp32 reference
// well within the 1.8e-2 threshold). Compile-time -> SGPR/inline, zero VGPRs.
__device__ __constant__ const float GW[11] = {
    0.00102838f, 0.00759876f, 0.03600075f, 0.10936075f, 0.21300700f,
    0.26601190f, 0.21300700f, 0.10936075f, 0.03600075f, 0.00759876f,
    0.00102838f};

__global__ __launch_bounds__(NTHR, 6)   // 6 waves/EU -> 6 blocks/CU, VGPR cap 85
void ssim_main(const float* __restrict__ img1, const float* __restrict__ img2,
               float* __restrict__ ws, float* __restrict__ out) {
    __shared__ float s1[11][LDSW];
    __shared__ float s2[11][LDSW];
    __shared__ float wred[NTHR / 64];

    const int t     = threadIdx.x;
    const int xb    = blockIdx.x & 1;                // column half: 0 or 1
    const int chunk = (blockIdx.x >> 1) & (CHUNKS - 1);
    const int img   = blockIdx.x >> 5;
    const int C0    = xb << 8;                       // 0 or 256
    const int R0    = chunk * CH;
    const int rows_out = min(CH, H - R0);            // 34, last chunk 2
    const int Gg    = (rows_out + 20) / 11;          // ceil((rows_out+10)/11)

    const float* __restrict__ b1 = img1 + (size_t)img * (H * W);
    const float* __restrict__ b2 = img2 + (size_t)img * (H * W);

    // pend[s*5 + q]: pending vertical accumulators for 11 in-flight output rows,
    // q in {mu1, mu2, e11, e22, e12}; 55 fp32 regs, all indices compile-time.
    float pend[55];
#pragma unroll
    for (int i = 0; i < 55; ++i) pend[i] = 0.f;

    float acc = 0.f;
    const float C1 = 0.0001f, C2 = 0.0009f;

    for (int grp = 0; grp < Gg; ++grp) {
        __syncthreads();
        {   // stage 11 padded rows (266 cols each) for both images
            const int j0 = R0 - 5 + grp * 11;
#pragma unroll
            for (int p = 0; p < 11; ++p) {
                const int jr = refl(j0 + p);
                const float* r1 = b1 + jr * W;
                const float* r2 = b2 + jr * W;
                for (int lc = t; lc < 266; lc += NTHR) {
                    const int gc = refl(C0 - 5 + lc);
                    s1[p][lc] = r1[gc];
                    s2[p][lc] = r2[gc];
                }
            }
        }
        __syncthreads();

#pragma unroll
        for (int p = 0; p < 11; ++p) {
            const int jj = grp * 11 + p;     // local h-row index

            // ---- horizontal blur: 5 quantities, this thread's column (lc = t+5)
            float h0 = 0.f, h1 = 0.f, h2 = 0.f, h3 = 0.f, h4 = 0.f;
#pragma unroll
            for (int k = 0; k < 11; ++k) {
                const float a = s1[p][t + k];     // taps lc = t .. t+10
                const float b = s2[p][t + k];
                const float w = GW[k];
                h0 = fmaf(w, a,     h0);
                h1 = fmaf(w, b,     h1);
                h2 = fmaf(w, a * a, h2);
                h3 = fmaf(w, b * b, h3);
                h4 = fmaf(w, a * b, h4);
            }

            // ---- vertical scatter: h-row jj contributes GW[d] to pending row jj-d
#pragma unroll
            for (int s_ = 0; s_ < 11; ++s_) {
                const int d = (p - s_ + 11) % 11;   // compile-time after unroll
                if (d == 0) {                       // output row jj starts
                    pend[s_ * 5 + 0] = GW[0] * h0;
                    pend[s_ * 5 + 1] = GW[0] * h1;
                    pend[s_ * 5 + 2] = GW[0] * h2;
                    pend[s_ * 5 + 3] = GW[0] * h3;
                    pend[s_ * 5 + 4] = GW[0] * h4;
                } else if (d == 10) {               // output row jj-10 completes
                    if (jj >= 10 && (jj - 10) < rows_out) {
                        const float mu1 = fmaf(GW[10], h0, pend[s_ * 5 + 0]);
                        const float mu2 = fmaf(GW[10], h1, pend[s_ * 5 + 1]);
                        const float e11 = fmaf(GW[10], h2, pend[s_ * 5 + 2]);
                        const float e22 = fmaf(GW[10], h3, pend[s_ * 5 + 3]);
                        const float e12 = fmaf(GW[10], h4, pend[s_ * 5 + 4]);
                        const float mu1s = mu1 * mu1, mu2s = mu2 * mu2;
                        const float m12  = mu1 * mu2;
                        const float num = (2.f * m12 + C1) * (2.f * (e12 - m12) + C2);
                        const float den = (mu1s + mu2s + C1) *
                                          ((e11 - mu1s) + (e22 - mu2s) + C2);
                        float ssim = num * __builtin_amdgcn_rcpf(den);
                        ssim = fminf(fmaxf(ssim, 0.f), 1.f);
                        acc += ssim;
                    }
                } else {
                    const float w = GW[d];
                    pend[s_ * 5 + 0] = fmaf(w, h0, pend[s_ * 5 + 0]);
                    pend[s_ * 5 + 1] = fmaf(w, h1, pend[s_ * 5 + 1]);
                    pend[s_ * 5 + 2] = fmaf(w, h2, pend[s_ * 5 + 2]);
                    pend[s_ * 5 + 3] = fmaf(w, h3, pend[s_ * 5 + 3]);
                    pend[s_ * 5 + 4] = fmaf(w, h4, pend[s_ * 5 + 4]);
                }
            }
        }
    }

    // ---- block reduction
#pragma unroll
    for (int off = 32; off > 0; off >>= 1) acc += __shfl_xor(acc, off);
    if ((t & 63) == 0) wred[t >> 6] = acc;
    __syncthreads();
    if (t == 0) {
        float tot = wred[0] + wred[1] + wred[2] + wred[3];
        // ws[0] = completion counter (uint), ws[1] = float accumulator; both
        // zeroed by hipMemsetAsync before this kernel each launch.
        atomicAdd(&ws[1], tot);
        __threadfence();
        unsigned old = atomicAdd((unsigned*)ws, 1u);
        if (old == NBLOCK - 1) {
            float total = atomicAdd(&ws[1], 0.f);   // coherent read-back
            out[0] = 1.0f - total / NPIX;
        }
    }
}

extern "C" void kernel_launch(void* const* d_in, const int* in_sizes, int n_in,
                              void* d_out, int out_size, void* d_ws, size_t ws_size,
                              hipStream_t stream) {
    const float* img1 = (const float*)d_in[0];
    const float* img2 = (const float*)d_in[1];
    float* out = (float*)d_out;
    float* ws  = (float*)d_ws;
    hipMemsetAsync(d_ws, 0, 16, stream);   // graph-safe (memset node)
    ssim_main<<<NBLOCK, NTHR, 0, stream>>>(img1, img2, ws, out);
}

// Round 3
// 206.481 us; speedup vs baseline: 1.3013x; 1.3013x over previous
//
#include <hip/hip_runtime.h>

#define NIMG   48
#define H      512
#define W      512
#define CH     34
#define CHUNKS 16
#define NTHR   256
#define LDSW   268          // 266 needed (256 cols + 2*5 halo), pad to 268
#define NBLOCK (NIMG * CHUNKS * 2)   // 1536
#define NPIX   12582912.0f

__device__ __forceinline__ int refl(int x) {
    x = (x < 0) ? -x : x;
    return (x >= 512) ? (1022 - x) : x;
}

// Gaussian weights sigma=1.5, window 11. constexpr + compile-time indexing
// -> inline literals, zero register / memory cost.
static constexpr float GW[11] = {
    0.00102838f, 0.00759876f, 0.03600075f, 0.10936075f, 0.21300700f,
    0.26601190f, 0.21300700f, 0.10936075f, 0.03600075f, 0.00759876f,
    0.00102838f};

__global__ __launch_bounds__(NTHR, 4)   // VGPR cap 128: pend[44]+working fits, NO spills
void ssim_main(const float* __restrict__ img1, const float* __restrict__ img2,
               float* __restrict__ partial) {
    __shared__ float ss[11][LDSW];   // s = x1 + x2
    __shared__ float sd[11][LDSW];   // d = x1 - x2
    __shared__ float wred[NTHR / 64];

    const int t     = threadIdx.x;
    const int xb    = blockIdx.x & 1;                // column half
    const int chunk = (blockIdx.x >> 1) & (CHUNKS - 1);
    const int img   = blockIdx.x >> 5;
    const int C0    = xb << 8;
    const int R0    = chunk * CH;
    const int rows_out = min(CH, H - R0);            // 34 (last chunk 2)
    const int Gg    = (rows_out + 20) / 11;

    const float* __restrict__ b1 = img1 + (size_t)img * (H * W);
    const float* __restrict__ b2 = img2 + (size_t)img * (H * W);

    // pend[slot*4 + q], q in {mu_s, mu_d, e_ss, e_dd}: vertical accumulators
    // for 11 in-flight output rows. 44 fp32 regs, all indices compile-time.
    float pend[44];
#pragma unroll
    for (int i = 0; i < 44; ++i) pend[i] = 0.f;

    float acc = 0.f;
    const float C1 = 0.0001f, C2 = 0.0009f;

    for (int grp = 0; grp < Gg; ++grp) {
        __syncthreads();
        {   // stage 11 padded rows: s and d
            const int j0 = R0 - 5 + grp * 11;
#pragma unroll
            for (int p = 0; p < 11; ++p) {
                const int jr = refl(j0 + p);
                const float* r1 = b1 + jr * W;
                const float* r2 = b2 + jr * W;
                for (int lc = t; lc < 266; lc += NTHR) {
                    const int gc = refl(C0 - 5 + lc);
                    const float a = r1[gc], b = r2[gc];
                    ss[p][lc] = a + b;
                    sd[p][lc] = a - b;
                }
            }
        }
        __syncthreads();

#pragma unroll
        for (int p = 0; p < 11; ++p) {
            const int jj = grp * 11 + p;     // local h-row index

            // ---- horizontal blur of {s, d, s^2, d^2} for column lc = t+5
            float h0 = 0.f, h1 = 0.f, h2 = 0.f, h3 = 0.f;
#pragma unroll
            for (int k = 0; k < 11; ++k) {
                const float sv = ss[p][t + k];
                const float dv = sd[p][t + k];
                const float w  = GW[k];
                h0 = fmaf(w, sv,      h0);
                h1 = fmaf(w, dv,      h1);
                h2 = fmaf(w, sv * sv, h2);
                h3 = fmaf(w, dv * dv, h3);
            }

            // ---- vertical scatter: h-row jj adds GW[dd] to pending row jj-dd
#pragma unroll
            for (int s_ = 0; s_ < 11; ++s_) {
                const int dd = (p - s_ + 11) % 11;   // compile-time after unroll
                if (dd == 0) {
                    pend[s_ * 4 + 0] = GW[0] * h0;
                    pend[s_ * 4 + 1] = GW[0] * h1;
                    pend[s_ * 4 + 2] = GW[0] * h2;
                    pend[s_ * 4 + 3] = GW[0] * h3;
                } else if (dd == 10) {               // output row jj-10 completes
                    if (jj >= 10 && (jj - 10) < rows_out) {
                        const float mu_s = fmaf(GW[10], h0, pend[s_ * 4 + 0]);
                        const float mu_d = fmaf(GW[10], h1, pend[s_ * 4 + 1]);
                        const float es   = fmaf(GW[10], h2, pend[s_ * 4 + 2]);
                        const float ed   = fmaf(GW[10], h3, pend[s_ * 4 + 3]);
                        const float P  = mu_s * mu_s;
                        const float Q  = mu_d * mu_d;
                        const float Vs = es - P;
                        const float Vd = ed - Q;
                        const float num = fmaf(0.5f, P - Q,   C1) *
                                          fmaf(0.5f, Vs - Vd, C2);
                        const float den = fmaf(0.5f, P + Q,   C1) *
                                          fmaf(0.5f, Vs + Vd, C2);
                        float ssim = num * __builtin_amdgcn_rcpf(den);
                        ssim = fminf(fmaxf(ssim, 0.f), 1.f);
                        acc += ssim;
                    }
                } else {
                    const float w = GW[dd];
                    pend[s_ * 4 + 0] = fmaf(w, h0, pend[s_ * 4 + 0]);
                    pend[s_ * 4 + 1] = fmaf(w, h1, pend[s_ * 4 + 1]);
                    pend[s_ * 4 + 2] = fmaf(w, h2, pend[s_ * 4 + 2]);
                    pend[s_ * 4 + 3] = fmaf(w, h3, pend[s_ * 4 + 3]);
                }
            }
        }
    }

    // ---- block reduction -> one partial per block
#pragma unroll
    for (int off = 32; off > 0; off >>= 1) acc += __shfl_xor(acc, off);
    if ((t & 63) == 0) wred[t >> 6] = acc;
    __syncthreads();
    if (t == 0)
        partial[blockIdx.x] = wred[0] + wred[1] + wred[2] + wred[3];
}

__global__ void ssim_finish(const float* __restrict__ partial, float* __restrict__ out) {
    float s = 0.f;
    for (int i = threadIdx.x; i < NBLOCK; i += 256) s += partial[i];
#pragma unroll
    for (int off = 32; off > 0; off >>= 1) s += __shfl_xor(s, off);
    __shared__ float wred[4];
    if ((threadIdx.x & 63) == 0) wred[threadIdx.x >> 6] = s;
    __syncthreads();
    if (threadIdx.x == 0)
        out[0] = 1.0f - (wred[0] + wred[1] + wred[2] + wred[3]) / NPIX;
}

extern "C" void kernel_launch(void* const* d_in, const int* in_sizes, int n_in,
                              void* d_out, int out_size, void* d_ws, size_t ws_size,
                              hipStream_t stream) {
    const float* img1 = (const float*)d_in[0];
    const float* img2 = (const float*)d_in[1];
    float* out = (float*)d_out;
    float* partial = (float*)d_ws;   // NBLOCK floats, all written each launch
    ssim_main<<<NBLOCK, NTHR, 0, stream>>>(img1, img2, partial);
    ssim_finish<<<1, 256, 0, stream>>>(partial, out);
}

// Round 4
// 193.125 us; speedup vs baseline: 1.3913x; 1.0692x over previous
//
#include <hip/hip_runtime.h>

typedef float v2f __attribute__((ext_vector_type(2)));

#define NIMG   48
#define H      512
#define W      512
#define CH     34
#define CHUNKS 16
#define NTHR   128          // 2 waves; each thread owns 2 adjacent columns
#define LDSW   268          // 266 needed, pad to 268 (keeps rows 8B-aligned)
#define NBLOCK (NIMG * CHUNKS * 2)   // 1536 = 6 blocks/CU (LDS-limited)
#define NPIX   12582912.0f

__device__ __forceinline__ int refl(int x) {
    x = (x < 0) ? -x : x;
    return (x >= 512) ? (1022 - x) : x;
}

// Gaussian weights sigma=1.5, window 11 (compile-time literals).
static constexpr float GWc[11] = {
    0.00102838f, 0.00759876f, 0.03600075f, 0.10936075f, 0.21300700f,
    0.26601190f, 0.21300700f, 0.10936075f, 0.03600075f, 0.00759876f,
    0.00102838f};

__device__ __forceinline__ v2f vfma(v2f a, v2f b, v2f c) {
    return __builtin_elementwise_fma(a, b, c);
}

__global__ __launch_bounds__(NTHR, 3)   // 3 waves/EU -> 170 VGPR cap, 6 blocks/CU
void ssim_main(const float* __restrict__ img1, const float* __restrict__ img2,
               float* __restrict__ partial) {
    __shared__ float ss[11][LDSW];   // s = x1 + x2
    __shared__ float sd[11][LDSW];   // d = x1 - x2
    __shared__ float wred[2];

    const int t     = threadIdx.x;
    const int xb    = blockIdx.x & 1;
    const int chunk = (blockIdx.x >> 1) & (CHUNKS - 1);
    const int img   = blockIdx.x >> 5;
    const int C0    = xb << 8;
    const int R0    = chunk * CH;
    const int rows_out = min(CH, H - R0);   // 34 (last chunk 2)
    const int Gg    = (rows_out + 20) / 11;

    const float* __restrict__ b1 = img1 + (size_t)img * (H * W);
    const float* __restrict__ b2 = img2 + (size_t)img * (H * W);

    // pend[slot*4 + q], q in {mu_s, mu_d, e_ss, e_dd}; v2f = 2 columns.
    v2f pend[44];
#pragma unroll
    for (int i = 0; i < 44; ++i) pend[i] = (v2f){0.f, 0.f};

    v2f acc = {0.f, 0.f};
    const float C1 = 0.0001f, C2 = 0.0009f;
    const v2f c1v = {C1, C1}, c2v = {C2, C2}, hv = {0.5f, 0.5f};

    for (int grp = 0; grp < Gg; ++grp) {
        __syncthreads();
        {   // stage 11 padded rows of s and d
            const int j0 = R0 - 5 + grp * 11;
#pragma unroll
            for (int p = 0; p < 11; ++p) {
                const int jr = refl(j0 + p);
                const float* r1 = b1 + jr * W;
                const float* r2 = b2 + jr * W;
                for (int lc = t; lc < 266; lc += NTHR) {
                    const int gc = refl(C0 - 5 + lc);
                    const float a = r1[gc], b = r2[gc];
                    ss[p][lc] = a + b;
                    sd[p][lc] = a - b;
                }
            }
        }
        __syncthreads();

#pragma unroll
        for (int p = 0; p < 11; ++p) {
            const int jj = grp * 11 + p;

            // ---- load the 12-float window (padded cols 2t..2t+11) as 6 aligned b64
            const v2f* f1 = (const v2f*)(&ss[p][0]);
            const v2f* f2 = (const v2f*)(&sd[p][0]);
            v2f w1[6], w2[6];
#pragma unroll
            for (int r = 0; r < 6; ++r) { w1[r] = f1[t + r]; w2[r] = f2[t + r]; }

            // ---- packed horizontal blur of {s, d, s^2, d^2} for the column pair
            v2f h0 = {0.f, 0.f}, h1 = {0.f, 0.f}, h2 = {0.f, 0.f}, h3 = {0.f, 0.f};
#pragma unroll
            for (int k = 0; k < 11; ++k) {
                const v2f ps = (k & 1)
                    ? __builtin_shufflevector(w1[k / 2], w1[k / 2 + 1], 1, 2)
                    : w1[k / 2];
                const v2f pd = (k & 1)
                    ? __builtin_shufflevector(w2[k / 2], w2[k / 2 + 1], 1, 2)
                    : w2[k / 2];
                const v2f wk = {GWc[k], GWc[k]};
                h0 = vfma(wk, ps, h0);
                h1 = vfma(wk, pd, h1);
                h2 = vfma(wk, ps * ps, h2);
                h3 = vfma(wk, pd * pd, h3);
            }

            // ---- vertical scatter into pending accumulators
#pragma unroll
            for (int s_ = 0; s_ < 11; ++s_) {
                const int dd = (p - s_ + 11) % 11;   // compile-time after unroll
                if (dd == 0) {
                    const v2f w0 = {GWc[0], GWc[0]};
                    pend[s_ * 4 + 0] = w0 * h0;
                    pend[s_ * 4 + 1] = w0 * h1;
                    pend[s_ * 4 + 2] = w0 * h2;
                    pend[s_ * 4 + 3] = w0 * h3;
                } else if (dd == 10) {               // output row jj-10 completes
                    if (jj >= 10 && (jj - 10) < rows_out) {
                        const v2f wA = {GWc[10], GWc[10]};
                        const v2f mu_s = vfma(wA, h0, pend[s_ * 4 + 0]);
                        const v2f mu_d = vfma(wA, h1, pend[s_ * 4 + 1]);
                        const v2f es   = vfma(wA, h2, pend[s_ * 4 + 2]);
                        const v2f ed   = vfma(wA, h3, pend[s_ * 4 + 3]);
                        const v2f P  = mu_s * mu_s;
                        const v2f Q  = mu_d * mu_d;
                        const v2f Vs = es - P;
                        const v2f Vd = ed - Q;
                        const v2f num = vfma(hv, P - Q,   c1v) * vfma(hv, Vs - Vd, c2v);
                        const v2f den = vfma(hv, P + Q,   c1v) * vfma(hv, Vs + Vd, c2v);
                        float r0 = num.x * __builtin_amdgcn_rcpf(den.x);
                        float r1 = num.y * __builtin_amdgcn_rcpf(den.y);
                        r0 = fminf(fmaxf(r0, 0.f), 1.f);
                        r1 = fminf(fmaxf(r1, 0.f), 1.f);
                        acc.x += r0;
                        acc.y += r1;
                    }
                } else {
                    const v2f w = {GWc[dd], GWc[dd]};
                    pend[s_ * 4 + 0] = vfma(w, h0, pend[s_ * 4 + 0]);
                    pend[s_ * 4 + 1] = vfma(w, h1, pend[s_ * 4 + 1]);
                    pend[s_ * 4 + 2] = vfma(w, h2, pend[s_ * 4 + 2]);
                    pend[s_ * 4 + 3] = vfma(w, h3, pend[s_ * 4 + 3]);
                }
            }
        }
    }

    // ---- block reduction (2 waves)
    float a = acc.x + acc.y;
#pragma unroll
    for (int off = 32; off > 0; off >>= 1) a += __shfl_xor(a, off);
    if ((t & 63) == 0) wred[t >> 6] = a;
    __syncthreads();
    if (t == 0) partial[blockIdx.x] = wred[0] + wred[1];
}

__global__ void ssim_finish(const float* __restrict__ partial, float* __restrict__ out) {
    float s = 0.f;
    for (int i = threadIdx.x; i < NBLOCK; i += 256) s += partial[i];
#pragma unroll
    for (int off = 32; off > 0; off >>= 1) s += __shfl_xor(s, off);
    __shared__ float wred[4];
    if ((threadIdx.x & 63) == 0) wred[threadIdx.x >> 6] = s;
    __syncthreads();
    if (threadIdx.x == 0)
        out[0] = 1.0f - (wred[0] + wred[1] + wred[2] + wred[3]) / NPIX;
}

extern "C" void kernel_launch(void* const* d_in, const int* in_sizes, int n_in,
                              void* d_out, int out_size, void* d_ws, size_t ws_size,
                              hipStream_t stream) {
    const float* img1 = (const float*)d_in[0];
    const float* img2 = (const float*)d_in[1];
    float* out = (float*)d_out;
    float* partial = (float*)d_ws;   // NBLOCK floats, all written each launch
    ssim_main<<<NBLOCK, NTHR, 0, stream>>>(img1, img2, partial);
    ssim_finish<<<1, 256, 0, stream>>>(partial, out);
}

// Round 5
// 161.375 us; speedup vs baseline: 1.6651x; 1.1967x over previous
//
#include <hip/hip_runtime.h>
#include <hip/hip_fp16.h>

#define NIMG   48
#define H      512
#define W      512
#define CH     16                       // output rows per block
#define RCH    32                       // row chunks (512/16)
#define CCH    4                        // col chunks
#define CW     128                      // cols per block
#define NTHR   64                       // 1 wave; 2 cols/thread
#define LDSW   144                      // 138 needed (128 + 2*5 halo), pad
#define HT     26                       // h-rows per block (CH + 10)
#define NBLOCK (NIMG * RCH * CCH)       // 6144 = 24 blocks/CU available
#define NPIX   12582912.0f

__device__ __forceinline__ int refl(int x) {
    x = (x < 0) ? -x : x;
    return (x >= 512) ? (1022 - x) : x;
}

// Gaussian weights sigma=1.5, window 11.
static constexpr float GWc[11] = {
    0.00102838f, 0.00759876f, 0.03600075f, 0.10936075f, 0.21300700f,
    0.26601190f, 0.21300700f, 0.10936075f, 0.03600075f, 0.00759876f,
    0.00102838f};

__device__ __forceinline__ float ssim_from(__half2 M, __half2 E,
                                           float C1, float C2) {
    // M = {mu_s' (s centered: s = x1+x2-1), mu_d}; E = {blur(s'^2), blur(d^2)}
    const float mup = __low2float(M);
    const float mud = __high2float(M);
    const float esp = __low2float(E);
    const float ed  = __high2float(E);
    const float mus = mup + 1.0f;                 // mu1 + mu2
    const float P   = mus * mus;                  // (mu1+mu2)^2
    const float Q   = mud * mud;                  // (mu1-mu2)^2
    const float Vs  = esp - mup * mup;            // sigma^2 of s (shift-invar.)
    const float Vd  = ed  - mud * mud;            // sigma^2 of d
    const float num = fmaf(0.5f, P - Q,  C1) * fmaf(0.5f, Vs - Vd, C2);
    const float den = fmaf(0.5f, P + Q,  C1) * fmaf(0.5f, Vs + Vd, C2);
    float s = num * __builtin_amdgcn_rcpf(den);
    return fminf(fmaxf(s, 0.f), 1.f);
}

__global__ __launch_bounds__(NTHR, 5)   // 5 waves/EU -> 20 blocks/CU, VGPR cap 102
void ssim_main(const float* __restrict__ img1, const float* __restrict__ img2,
               float* __restrict__ partial) {
    __shared__ __half2 sdl[11][LDSW];   // {s-1, d} per pixel, fp16

    const int t     = threadIdx.x;
    const int xb    = blockIdx.x & 3;
    const int chunk = (blockIdx.x >> 2) & (RCH - 1);
    const int img   = blockIdx.x >> 7;
    const int C0    = xb * CW;
    const int R0    = chunk * CH;

    const float* __restrict__ b1 = img1 + (size_t)img * (H * W);
    const float* __restrict__ b2 = img2 + (size_t)img * (H * W);

    // fp16 weight splats (uniform; compiler folds/keeps in SGPRs)
    __half2 wh[11];
#pragma unroll
    for (int k = 0; k < 11; ++k) wh[k] = __float2half2_rn(GWc[k]);

    // Vertical pending accumulators: 11 slots x {A,B: mu col0/col1, C,D: E col0/col1}
    __half2 pA[11], pB[11], pC[11], pD[11];
#pragma unroll
    for (int i = 0; i < 11; ++i) {
        pA[i] = __float2half2_rn(0.f); pB[i] = pA[i];
        pC[i] = pA[i];                 pD[i] = pA[i];
    }

    float acc = 0.f;
    const float C1 = 0.0001f, C2 = 0.0009f;

    for (int grp = 0; grp < 3; ++grp) {
        const int base  = grp * 11;
        const int nrows = (grp == 2) ? (HT - 22) : 11;   // 11,11,4
        __syncthreads();
        for (int p = 0; p < nrows; ++p) {
            const int jr = refl(R0 - 5 + base + p);
            const float* r1 = b1 + jr * W;
            const float* r2 = b2 + jr * W;
#pragma unroll
            for (int it = 0; it < 3; ++it) {
                const int lc = t + it * 64;
                if (it < 2 || lc < 138) {
                    const int gc = refl(C0 - 5 + lc);
                    const float a = r1[gc], b = r2[gc];
                    sdl[p][lc] = __floats2half2_rn(a + b - 1.0f, a - b);
                }
            }
        }
        __syncthreads();

#pragma unroll
        for (int p = 0; p < 11; ++p) {
            const int jj = base + p;
            if (jj < HT) {
                // ---- window: padded cols 2t .. 2t+11 as 6 aligned b64 reads
                const float2* wp = (const float2*)(&sdl[p][2 * t]);
                float2 wr[6];
#pragma unroll
                for (int r = 0; r < 6; ++r) wr[r] = wp[r];
                __half2 sd[12];
#pragma unroll
                for (int r = 0; r < 6; ++r) {
                    sd[2 * r]     = __builtin_bit_cast(__half2, wr[r].x);
                    sd[2 * r + 1] = __builtin_bit_cast(__half2, wr[r].y);
                }
                // squares shared by both columns
                __half2 sq[12];
#pragma unroll
                for (int j = 0; j < 12; ++j) sq[j] = __hmul2(sd[j], sd[j]);

                // ---- packed horizontal blur, cols c0 (taps 0..10), c1 (taps 1..11)
                __half2 hM0 = __float2half2_rn(0.f), hE0 = hM0;
                __half2 hM1 = hM0, hE1 = hM0;
#pragma unroll
                for (int k = 0; k < 11; ++k) {
                    hM0 = __hfma2(wh[k], sd[k],     hM0);
                    hE0 = __hfma2(wh[k], sq[k],     hE0);
                    hM1 = __hfma2(wh[k], sd[k + 1], hM1);
                    hE1 = __hfma2(wh[k], sq[k + 1], hE1);
                }

                // ---- vertical scatter into pending slots
#pragma unroll
                for (int s_ = 0; s_ < 11; ++s_) {
                    const int dd = (p - s_ + 11) % 11;   // compile-time
                    if (dd == 0) {
                        pA[s_] = __hmul2(wh[0], hM0);
                        pB[s_] = __hmul2(wh[0], hM1);
                        pC[s_] = __hmul2(wh[0], hE0);
                        pD[s_] = __hmul2(wh[0], hE1);
                    } else if (dd == 10) {
                        if (jj >= 10) {                  // out row jj-10 in [0,16)
                            const __half2 A = __hfma2(wh[10], hM0, pA[s_]);
                            const __half2 B = __hfma2(wh[10], hM1, pB[s_]);
                            const __half2 Cq = __hfma2(wh[10], hE0, pC[s_]);
                            const __half2 Dq = __hfma2(wh[10], hE1, pD[s_]);
                            acc += ssim_from(A, Cq, C1, C2);
                            acc += ssim_from(B, Dq, C1, C2);
                        }
                    } else {
                        pA[s_] = __hfma2(wh[dd], hM0, pA[s_]);
                        pB[s_] = __hfma2(wh[dd], hM1, pB[s_]);
                        pC[s_] = __hfma2(wh[dd], hE0, pC[s_]);
                        pD[s_] = __hfma2(wh[dd], hE1, pD[s_]);
                    }
                }
            }
        }
    }

    // ---- single-wave reduction
#pragma unroll
    for (int off = 32; off > 0; off >>= 1) acc += __shfl_xor(acc, off);
    if (t == 0) partial[blockIdx.x] = acc;
}

__global__ void ssim_finish(const float* __restrict__ partial, float* __restrict__ out) {
    float s = 0.f;
    for (int i = threadIdx.x; i < NBLOCK; i += 256) s += partial[i];
#pragma unroll
    for (int off = 32; off > 0; off >>= 1) s += __shfl_xor(s, off);
    __shared__ float wred[4];
    if ((threadIdx.x & 63) == 0) wred[threadIdx.x >> 6] = s;
    __syncthreads();
    if (threadIdx.x == 0)
        out[0] = 1.0f - (wred[0] + wred[1] + wred[2] + wred[3]) / NPIX;
}

extern "C" void kernel_launch(void* const* d_in, const int* in_sizes, int n_in,
                              void* d_out, int out_size, void* d_ws, size_t ws_size,
                              hipStream_t stream) {
    const float* img1 = (const float*)d_in[0];
    const float* img2 = (const float*)d_in[1];
    float* out = (float*)d_out;
    float* partial = (float*)d_ws;   // NBLOCK floats, all written each launch
    ssim_main<<<NBLOCK, NTHR, 0, stream>>>(img1, img2, partial);
    ssim_finish<<<1, 256, 0, stream>>>(partial, out);
}

// Round 6
// 160.653 us; speedup vs baseline: 1.6725x; 1.0045x over previous
//
#include <hip/hip_runtime.h>
#include <hip/hip_fp16.h>

#define NIMG   48
#define H      512
#define W      512
#define CH     16                       // output rows per block
#define RCH    32                       // row chunks (512/16)
#define CCH    4                        // col chunks
#define CW     128                      // cols per block
#define NTHR   64                       // 1 wave; 2 cols/thread
#define LDSW   144                      // 138 needed (128 + 2*5 halo), pad
#define HT     26                       // h-rows per block (CH + 10)
#define NBLOCK (NIMG * RCH * CCH)       // 6144 = 24 blocks/CU
#define NPIX   12582912.0f

__device__ __forceinline__ int refl(int x) {
    x = (x < 0) ? -x : x;
    return (x >= 512) ? (1022 - x) : x;
}

// Gaussian weights sigma=1.5, window 11.
static constexpr float GWc[11] = {
    0.00102838f, 0.00759876f, 0.03600075f, 0.10936075f, 0.21300700f,
    0.26601190f, 0.21300700f, 0.10936075f, 0.03600075f, 0.00759876f,
    0.00102838f};

__device__ __forceinline__ float ssim_from(__half2 M, __half2 E,
                                           float C1, float C2) {
    // M = {mu_s' (s centered: s = x1+x2-1), mu_d}; E = {blur(s'^2), blur(d^2)}
    const float mup = __low2float(M);
    const float mud = __high2float(M);
    const float esp = __low2float(E);
    const float ed  = __high2float(E);
    const float mus = mup + 1.0f;
    const float P   = mus * mus;
    const float Q   = mud * mud;
    const float Vs  = esp - mup * mup;
    const float Vd  = ed  - mud * mud;
    const float num = fmaf(0.5f, P - Q,  C1) * fmaf(0.5f, Vs - Vd, C2);
    const float den = fmaf(0.5f, P + Q,  C1) * fmaf(0.5f, Vs + Vd, C2);
    float s = num * __builtin_amdgcn_rcpf(den);
    return fminf(fmaxf(s, 0.f), 1.f);
}

__global__ __launch_bounds__(NTHR, 6)   // 6 waves/EU: 85-reg cap, 24 waves/CU = grid cap
void ssim_main(const float* __restrict__ img1, const float* __restrict__ img2,
               float* __restrict__ partial) {
    __shared__ __half2 sdl[11][LDSW];   // {s-1, d} per pixel, fp16

    const int t     = threadIdx.x;
    const int xb    = blockIdx.x & 3;
    const int chunk = (blockIdx.x >> 2) & (RCH - 1);
    const int img   = blockIdx.x >> 7;
    const int C0    = xb * CW;
    const int R0    = chunk * CH;

    const float* __restrict__ b1 = img1 + (size_t)img * (H * W);
    const float* __restrict__ b2 = img2 + (size_t)img * (H * W);

    // Row-invariant staging columns: hoisted out of the 26-row loop.
    const int gc0 = refl(C0 - 5 + t);
    const int gc1 = refl(C0 - 5 + t + 64);
    const int gc2 = (t + 128 < 138) ? refl(C0 - 5 + t + 128) : 0;
    const bool l2 = (t + 128) < 138;

    // fp16 weight splats (wave-uniform -> SGPR operands for VOP3P)
    __half2 wh[11];
#pragma unroll
    for (int k = 0; k < 11; ++k) wh[k] = __float2half2_rn(GWc[k]);

    __half2 pA[11], pB[11], pC[11], pD[11];
#pragma unroll
    for (int i = 0; i < 11; ++i) {
        pA[i] = __float2half2_rn(0.f); pB[i] = pA[i];
        pC[i] = pA[i];                 pD[i] = pA[i];
    }

    float acc = 0.f;
    const float C1 = 0.0001f, C2 = 0.0009f;

    for (int grp = 0; grp < 3; ++grp) {
        const int base  = grp * 11;
        const int nrows = (grp == 2) ? (HT - 22) : 11;   // 11,11,4
        __syncthreads();
        for (int p = 0; p < nrows; ++p) {
            const int jr = refl(R0 - 5 + base + p);
            const float* r1 = b1 + jr * W;
            const float* r2 = b2 + jr * W;
            {
                const float a0 = r1[gc0], b0 = r2[gc0];
                const float a1 = r1[gc1], b1v = r2[gc1];
                sdl[p][t]      = __floats2half2_rn(a0 + b0 - 1.0f, a0 - b0);
                sdl[p][t + 64] = __floats2half2_rn(a1 + b1v - 1.0f, a1 - b1v);
                if (l2) {
                    const float a2 = r1[gc2], b2v = r2[gc2];
                    sdl[p][t + 128] = __floats2half2_rn(a2 + b2v - 1.0f, a2 - b2v);
                }
            }
        }
        __syncthreads();

#pragma unroll
        for (int p = 0; p < 11; ++p) {
            const int jj = base + p;
            if (jj < HT) {
                const float2* wp = (const float2*)(&sdl[p][2 * t]);
                float2 wr[6];
#pragma unroll
                for (int r = 0; r < 6; ++r) wr[r] = wp[r];
                __half2 sd[12];
#pragma unroll
                for (int r = 0; r < 6; ++r) {
                    sd[2 * r]     = __builtin_bit_cast(__half2, wr[r].x);
                    sd[2 * r + 1] = __builtin_bit_cast(__half2, wr[r].y);
                }
                __half2 sq[12];
#pragma unroll
                for (int j = 0; j < 12; ++j) sq[j] = __hmul2(sd[j], sd[j]);

                __half2 hM0 = __float2half2_rn(0.f), hE0 = hM0;
                __half2 hM1 = hM0, hE1 = hM0;
#pragma unroll
                for (int k = 0; k < 11; ++k) {
                    hM0 = __hfma2(wh[k], sd[k],     hM0);
                    hE0 = __hfma2(wh[k], sq[k],     hE0);
                    hM1 = __hfma2(wh[k], sd[k + 1], hM1);
                    hE1 = __hfma2(wh[k], sq[k + 1], hE1);
                }

#pragma unroll
                for (int s_ = 0; s_ < 11; ++s_) {
                    const int dd = (p - s_ + 11) % 11;   // compile-time
                    if (dd == 0) {
                        pA[s_] = __hmul2(wh[0], hM0);
                        pB[s_] = __hmul2(wh[0], hM1);
                        pC[s_] = __hmul2(wh[0], hE0);
                        pD[s_] = __hmul2(wh[0], hE1);
                    } else if (dd == 10) {
                        if (jj >= 10) {
                            const __half2 A  = __hfma2(wh[10], hM0, pA[s_]);
                            const __half2 B  = __hfma2(wh[10], hM1, pB[s_]);
                            const __half2 Cq = __hfma2(wh[10], hE0, pC[s_]);
                            const __half2 Dq = __hfma2(wh[10], hE1, pD[s_]);
                            acc += ssim_from(A, Cq, C1, C2);
                            acc += ssim_from(B, Dq, C1, C2);
                        }
                    } else {
                        pA[s_] = __hfma2(wh[dd], hM0, pA[s_]);
                        pB[s_] = __hfma2(wh[dd], hM1, pB[s_]);
                        pC[s_] = __hfma2(wh[dd], hE0, pC[s_]);
                        pD[s_] = __hfma2(wh[dd], hE1, pD[s_]);
                    }
                }
            }
        }
    }

#pragma unroll
    for (int off = 32; off > 0; off >>= 1) acc += __shfl_xor(acc, off);
    if (t == 0) partial[blockIdx.x] = acc;
}

__global__ void ssim_finish(const float* __restrict__ partial, float* __restrict__ out) {
    float s = 0.f;
    for (int i = threadIdx.x; i < NBLOCK; i += 256) s += partial[i];
#pragma unroll
    for (int off = 32; off > 0; off >>= 1) s += __shfl_xor(s, off);
    __shared__ float wred[4];
    if ((threadIdx.x & 63) == 0) wred[threadIdx.x >> 6] = s;
    __syncthreads();
    if (threadIdx.x == 0)
        out[0] = 1.0f - (wred[0] + wred[1] + wred[2] + wred[3]) / NPIX;
}

extern "C" void kernel_launch(void* const* d_in, const int* in_sizes, int n_in,
                              void* d_out, int out_size, void* d_ws, size_t ws_size,
                              hipStream_t stream) {
    const float* img1 = (const float*)d_in[0];
    const float* img2 = (const float*)d_in[1];
    float* out = (float*)d_out;
    float* partial = (float*)d_ws;
    ssim_main<<<NBLOCK, NTHR, 0, stream>>>(img1, img2, partial);
    ssim_finish<<<1, 256, 0, stream>>>(partial, out);
}

// Round 7
// 159.823 us; speedup vs baseline: 1.6812x; 1.0052x over previous
//
#include <hip/hip_runtime.h>
#include <hip/hip_fp16.h>

#define NIMG   48
#define H      512
#define W      512
#define CH     16                       // output rows per block
#define RCH    32                       // row chunks (512/16)
#define CCH    2                        // col chunks
#define CW     256                      // cols per block
#define NTHR   128                      // 2 waves; 2 cols/thread
#define LDSW   268                      // 266 needed (256 + 2*5 halo), pad
#define HT     26                       // h-rows per block (CH + 10)
#define NBLOCK (NIMG * RCH * CCH)       // 3072 = 12 blocks/CU x 2 waves = 24 waves/CU
#define NPIX   12582912.0f

__device__ __forceinline__ int refl(int x) {
    x = (x < 0) ? -x : x;
    return (x >= 512) ? (1022 - x) : x;
}

// Gaussian weights sigma=1.5, window 11.
static constexpr float GWc[11] = {
    0.00102838f, 0.00759876f, 0.03600075f, 0.10936075f, 0.21300700f,
    0.26601190f, 0.21300700f, 0.10936075f, 0.03600075f, 0.00759876f,
    0.00102838f};

__device__ __forceinline__ float ssim_from(__half2 M, __half2 E,
                                           float C1, float C2) {
    // M = {mu_s' (s centered: s = x1+x2-1), mu_d}; E = {blur(s'^2), blur(d^2)}
    const float mup = __low2float(M);
    const float mud = __high2float(M);
    const float esp = __low2float(E);
    const float ed  = __high2float(E);
    const float mus = mup + 1.0f;
    const float P   = mus * mus;
    const float Q   = mud * mud;
    const float Vs  = esp - mup * mup;
    const float Vd  = ed  - mud * mud;
    const float num = fmaf(0.5f, P - Q,  C1) * fmaf(0.5f, Vs - Vd, C2);
    const float den = fmaf(0.5f, P + Q,  C1) * fmaf(0.5f, Vs + Vd, C2);
    float s = num * __builtin_amdgcn_rcpf(den);
    return fminf(fmaxf(s, 0.f), 1.f);
}

__global__ __launch_bounds__(NTHR, 6)   // cap 85 regs; plenty (measured 40)
void ssim_main(const float* __restrict__ img1, const float* __restrict__ img2,
               float* __restrict__ partial) {
    __shared__ __half2 sdl[11][LDSW];   // {s-1, d} per pixel, fp16

    const int t     = threadIdx.x;
    const int xb    = blockIdx.x & 1;
    const int chunk = (blockIdx.x >> 1) & (RCH - 1);
    const int img   = blockIdx.x >> 6;
    const int C0    = xb * CW;
    const int R0    = chunk * CH;

    const float* __restrict__ b1 = img1 + (size_t)img * (H * W);
    const float* __restrict__ b2 = img2 + (size_t)img * (H * W);

    // Row-invariant staging columns (266 half2 per row, 128 threads -> 2+partial)
    const int gc0 = refl(C0 - 5 + t);
    const int gc1 = refl(C0 - 5 + t + 128);
    const int gc2 = (t + 256 < 266) ? refl(C0 - 5 + t + 256) : 0;
    const bool l2 = (t + 256) < 266;

    __half2 wh[11];
#pragma unroll
    for (int k = 0; k < 11; ++k) wh[k] = __float2half2_rn(GWc[k]);

    __half2 pA[11], pB[11], pC[11], pD[11];
#pragma unroll
    for (int i = 0; i < 11; ++i) {
        pA[i] = __float2half2_rn(0.f); pB[i] = pA[i];
        pC[i] = pA[i];                 pD[i] = pA[i];
    }

    float acc = 0.f;
    const float C1 = 0.0001f, C2 = 0.0009f;

    for (int grp = 0; grp < 3; ++grp) {
        const int base  = grp * 11;
        const int nrows = (grp == 2) ? (HT - 22) : 11;   // 11,11,4
        __syncthreads();
        for (int p = 0; p < nrows; ++p) {
            const int jr = refl(R0 - 5 + base + p);
            const float* r1 = b1 + jr * W;
            const float* r2 = b2 + jr * W;
            {
                const float a0 = r1[gc0], b0 = r2[gc0];
                const float a1 = r1[gc1], b1v = r2[gc1];
                sdl[p][t]       = __floats2half2_rn(a0 + b0 - 1.0f, a0 - b0);
                sdl[p][t + 128] = __floats2half2_rn(a1 + b1v - 1.0f, a1 - b1v);
                if (l2) {
                    const float a2 = r1[gc2], b2v = r2[gc2];
                    sdl[p][t + 256] = __floats2half2_rn(a2 + b2v - 1.0f, a2 - b2v);
                }
            }
        }
        __syncthreads();

#pragma unroll
        for (int p = 0; p < 11; ++p) {
            const int jj = base + p;
            if (jj < HT) {
                const float2* wp = (const float2*)(&sdl[p][2 * t]);
                float2 wr[6];
#pragma unroll
                for (int r = 0; r < 6; ++r) wr[r] = wp[r];
                __half2 sd[12];
#pragma unroll
                for (int r = 0; r < 6; ++r) {
                    sd[2 * r]     = __builtin_bit_cast(__half2, wr[r].x);
                    sd[2 * r + 1] = __builtin_bit_cast(__half2, wr[r].y);
                }
                __half2 sq[12];
#pragma unroll
                for (int j = 0; j < 12; ++j) sq[j] = __hmul2(sd[j], sd[j]);

                __half2 hM0 = __float2half2_rn(0.f), hE0 = hM0;
                __half2 hM1 = hM0, hE1 = hM0;
#pragma unroll
                for (int k = 0; k < 11; ++k) {
                    hM0 = __hfma2(wh[k], sd[k],     hM0);
                    hE0 = __hfma2(wh[k], sq[k],     hE0);
                    hM1 = __hfma2(wh[k], sd[k + 1], hM1);
                    hE1 = __hfma2(wh[k], sq[k + 1], hE1);
                }

#pragma unroll
                for (int s_ = 0; s_ < 11; ++s_) {
                    const int dd = (p - s_ + 11) % 11;   // compile-time
                    if (dd == 0) {
                        pA[s_] = __hmul2(wh[0], hM0);
                        pB[s_] = __hmul2(wh[0], hM1);
                        pC[s_] = __hmul2(wh[0], hE0);
                        pD[s_] = __hmul2(wh[0], hE1);
                    } else if (dd == 10) {
                        if (jj >= 10) {
                            const __half2 A  = __hfma2(wh[10], hM0, pA[s_]);
                            const __half2 B  = __hfma2(wh[10], hM1, pB[s_]);
                            const __half2 Cq = __hfma2(wh[10], hE0, pC[s_]);
                            const __half2 Dq = __hfma2(wh[10], hE1, pD[s_]);
                            acc += ssim_from(A, Cq, C1, C2);
                            acc += ssim_from(B, Dq, C1, C2);
                        }
                    } else {
                        pA[s_] = __hfma2(wh[dd], hM0, pA[s_]);
                        pB[s_] = __hfma2(wh[dd], hM1, pB[s_]);
                        pC[s_] = __hfma2(wh[dd], hE0, pC[s_]);
                        pD[s_] = __hfma2(wh[dd], hE1, pD[s_]);
                    }
                }
            }
        }
    }

    // ---- block reduction (2 waves)
#pragma unroll
    for (int off = 32; off > 0; off >>= 1) acc += __shfl_xor(acc, off);
    __shared__ float wred[2];
    if ((t & 63) == 0) wred[t >> 6] = acc;
    __syncthreads();
    if (t == 0) partial[blockIdx.x] = wred[0] + wred[1];
}

__global__ void ssim_finish(const float* __restrict__ partial, float* __restrict__ out) {
    float s = 0.f;
    for (int i = threadIdx.x; i < NBLOCK; i += 256) s += partial[i];
#pragma unroll
    for (int off = 32; off > 0; off >>= 1) s += __shfl_xor(s, off);
    __shared__ float wred[4];
    if ((threadIdx.x & 63) == 0) wred[threadIdx.x >> 6] = s;
    __syncthreads();
    if (threadIdx.x == 0)
        out[0] = 1.0f - (wred[0] + wred[1] + wred[2] + wred[3]) / NPIX;
}

extern "C" void kernel_launch(void* const* d_in, const int* in_sizes, int n_in,
                              void* d_out, int out_size, void* d_ws, size_t ws_size,
                              hipStream_t stream) {
    const float* img1 = (const float*)d_in[0];
    const float* img2 = (const float*)d_in[1];
    float* out = (float*)d_out;
    float* partial = (float*)d_ws;
    ssim_main<<<NBLOCK, NTHR, 0, stream>>>(img1, img2, partial);
    ssim_finish<<<1, 256, 0, stream>>>(partial, out);
}